// Round 1
// baseline (1531.166 us; speedup 1.0000x reference)
//
#include <hip/hip_runtime.h>
#include <hip/hip_fp16.h>
#include <math.h>

#define NN 20000
#define EE 200000
// MUL=128, D=512, EDGE_ATTR=32, HID=32

__device__ __forceinline__ float sspf(float x){
    float sp = (x > 20.f) ? x : log1pf(expf(x));
    return sp - 0.69314718056f;
}

__device__ __forceinline__ void fma8(float* acc, const float* base, float w){
    const float4 a = ((const float4*)base)[0];
    const float4 b = ((const float4*)base)[1];
    acc[0]+=a.x*w; acc[1]+=a.y*w; acc[2]+=a.z*w; acc[3]+=a.w*w;
    acc[4]+=b.x*w; acc[5]+=b.y*w; acc[6]+=b.z*w; acc[7]+=b.w*w;
}

// ---------------- K1: pre irrep_linear -> p1, sdst (p0 consumed in-LDS) ----
__global__ __launch_bounds__(256) void k_pre(
    const float* __restrict__ x, const float* __restrict__ Wp0,
    const float* __restrict__ bp0, const float* __restrict__ Wp1,
    const float* __restrict__ Ws1,
    float* __restrict__ p1, float* __restrict__ sdst)
{
    __shared__ float xl[512][8];    // transposed [feature][node]
    __shared__ float p0l[8][128];
    const int tid = threadIdx.x;
    const int n0 = blockIdx.x * 8;

    for (int it = 0; it < 4; ++it){
        int idx = tid + 256*it;           // 0..1023 float4 slots
        int node = idx >> 7, o4 = idx & 127;
        float4 v = ((const float4*)(x + (size_t)(n0+node)*512))[o4];
        xl[o4*4+0][node]=v.x; xl[o4*4+1][node]=v.y;
        xl[o4*4+2][node]=v.z; xl[o4*4+3][node]=v.w;
    }
    __syncthreads();

    const int j = tid;
    float acc1[8] = {0,0,0,0,0,0,0,0};
    float acc2[8] = {0,0,0,0,0,0,0,0};
    const int o2 = j + 128;               // p1-index in [128,384)
    const int v2 = o2/3, m2 = o2%3;

    if (j < 128){
        for (int u = 0; u < 128; ++u){
            float w1 = Wp0[u*128 + j];
            float w2 = Wp1[u*128 + v2];
            fma8(acc1, &xl[u][0], w1);
            fma8(acc2, &xl[128 + u*3 + m2][0], w2);
        }
        float b = bp0[j];
        #pragma unroll
        for (int n = 0; n < 8; ++n) p0l[n][j] = acc1[n] + b;
    } else {
        const int o1 = j - 128, v1 = o1/3, m1 = o1%3;
        for (int u = 0; u < 128; ++u){
            float w1 = Wp1[u*128 + v1];
            float w2 = Wp1[u*128 + v2];
            fma8(acc1, &xl[128 + u*3 + m1][0], w1);
            fma8(acc2, &xl[128 + u*3 + m2][0], w2);
        }
        #pragma unroll
        for (int n = 0; n < 8; ++n) p1[(size_t)(n0+n)*384 + (j-128)] = acc1[n];
    }
    #pragma unroll
    for (int n = 0; n < 8; ++n) p1[(size_t)(n0+n)*384 + o2] = acc2[n];
    __syncthreads();

    // sdst = p0 @ (Ws1[0:128] + Ws1[128:256])  (the dst-only part of s0@W_s1)
    {
        int n = tid >> 5, h = tid & 31;
        float s = 0.f;
        for (int u = 0; u < 128; ++u){
            float wc = Ws1[u*32 + h] + Ws1[(128+u)*32 + h];
            s += p0l[n][u] * wc;
        }
        sdst[(size_t)(n0+n)*32 + h] = s;
    }
}

// ---------------- K2: gate + node irrep_linear -> self_x -------------------
__global__ __launch_bounds__(256) void k_gate_nd(
    const float* __restrict__ x,
    const float* __restrict__ Wg1, const float* __restrict__ bg1,
    const float* __restrict__ Wg2, const float* __restrict__ bg2,
    const float* __restrict__ Wnd0, const float* __restrict__ bnd0,
    const float* __restrict__ Wnd1,
    float* __restrict__ self_x)
{
    __shared__ float xl[512][8];
    __shared__ float tl[256][8];   // t, then reused for g
    __shared__ float hl[256][8];
    const int tid = threadIdx.x;
    const int n0 = blockIdx.x * 8;

    for (int it = 0; it < 4; ++it){
        int idx = tid + 256*it;
        int node = idx >> 7, o4 = idx & 127;
        float4 v = ((const float4*)(x + (size_t)(n0+node)*512))[o4];
        xl[o4*4+0][node]=v.x; xl[o4*4+1][node]=v.y;
        xl[o4*4+2][node]=v.z; xl[o4*4+3][node]=v.w;
    }
    __syncthreads();

    { // t = [x0, n1]
        int jj = tid;
        if (jj < 128){
            #pragma unroll
            for (int n = 0; n < 8; ++n) tl[jj][n] = xl[jj][n];
        } else {
            int u = jj - 128;
            #pragma unroll
            for (int n = 0; n < 8; ++n){
                float a = xl[128+u*3][n], b = xl[128+u*3+1][n], c = xl[128+u*3+2][n];
                tl[jj][n] = sqrtf((a*a + b*b + c*c) * (1.f/3.f));
            }
        }
    }
    __syncthreads();

    { // h = silu(t @ Wg1 + bg1)
        float acc[8] = {0,0,0,0,0,0,0,0};
        for (int k = 0; k < 256; ++k){
            float w = Wg1[k*256 + tid];
            fma8(acc, &tl[k][0], w);
        }
        float b = bg1[tid];
        #pragma unroll
        for (int n = 0; n < 8; ++n){
            float v = acc[n] + b;
            hl[tid][n] = v / (1.f + expf(-v));
        }
    }
    __syncthreads();

    { // g = h @ Wg2 + bg2  (stored into tl; tl is dead after the barrier)
        float acc[8] = {0,0,0,0,0,0,0,0};
        for (int k = 0; k < 256; ++k){
            float w = Wg2[k*256 + tid];
            fma8(acc, &hl[k][0], w);
        }
        float b = bg2[tid];
        #pragma unroll
        for (int n = 0; n < 8; ++n) tl[tid][n] = acc[n] + b;
    }
    __syncthreads();

    { // xg in-place into xl
        int jj = tid;
        if (jj < 128){
            #pragma unroll
            for (int n = 0; n < 8; ++n) xl[jj][n] = tl[jj][n];
        } else {
            int u = jj - 128;
            #pragma unroll
            for (int n = 0; n < 8; ++n){
                float g1 = tl[128+u][n];
                xl[128+u*3  ][n] *= g1;
                xl[128+u*3+1][n] *= g1;
                xl[128+u*3+2][n] *= g1;
            }
        }
    }
    __syncthreads();

    // nd irrep_linear
    const int j = tid;
    float acc1[8] = {0,0,0,0,0,0,0,0};
    float acc2[8] = {0,0,0,0,0,0,0,0};
    const int o2 = j + 128;
    const int v2 = o2/3, m2 = o2%3;
    if (j < 128){
        for (int u = 0; u < 128; ++u){
            float w1 = Wnd0[u*128 + j];
            float w2 = Wnd1[u*128 + v2];
            fma8(acc1, &xl[u][0], w1);
            fma8(acc2, &xl[128 + u*3 + m2][0], w2);
        }
        float b = bnd0[j];
        #pragma unroll
        for (int n = 0; n < 8; ++n) self_x[(size_t)(n0+n)*512 + j] = acc1[n] + b;
    } else {
        const int o1 = j - 128, v1 = o1/3, m1 = o1%3;
        for (int u = 0; u < 128; ++u){
            float w1 = Wnd1[u*128 + v1];
            float w2 = Wnd1[u*128 + v2];
            fma8(acc1, &xl[128 + u*3 + m1][0], w1);
            fma8(acc2, &xl[128 + u*3 + m2][0], w2);
        }
        #pragma unroll
        for (int n = 0; n < 8; ++n) self_x[(size_t)(n0+n)*512 + j] = acc1[n];
    }
    #pragma unroll
    for (int n = 0; n < 8; ++n) self_x[(size_t)(n0+n)*512 + j + 256] = acc2[n];
}

// ---------------- K3: edge features -> fbuf, sbuf (E x 32 each) ------------
__global__ __launch_bounds__(256) void k_edge_pre(
    const float* __restrict__ p1g, const float* __restrict__ sdst,
    const float* __restrict__ ea, const int* __restrict__ eidx,
    const float* __restrict__ Wf1, const float* __restrict__ Ws1,
    float* __restrict__ fbuf, float* __restrict__ sbuf)
{
    __shared__ float p1d[8][384], p1s[8][384];
    __shared__ float eal[8][32], sdl[8][32];
    __shared__ float ip1l[8][128];
    __shared__ int il[8][2];
    const int tid = threadIdx.x;
    const long e0 = (long)blockIdx.x * 8;

    if (tid < 16){
        int e = tid & 7;
        il[e][tid>>3] = eidx[(size_t)(tid>>3)*EE + e0 + e];
    }
    __syncthreads();

    for (int e = 0; e < 8; ++e){
        int dst = il[e][0], src = il[e][1];
        if (tid < 96)
            ((float4*)p1d[e])[tid] = ((const float4*)(p1g + (size_t)dst*384))[tid];
        else if (tid < 192)
            ((float4*)p1s[e])[tid-96] = ((const float4*)(p1g + (size_t)src*384))[tid-96];
        else if (tid < 200)
            ((float4*)eal[e])[tid-192] = ((const float4*)(ea + (e0+e)*32))[tid-192];
        else if (tid < 208)
            ((float4*)sdl[e])[tid-200] = ((const float4*)(sdst + (size_t)dst*32))[tid-200];
    }
    __syncthreads();

    for (int it = 0; it < 4; ++it){
        int idx = tid + 256*it;
        int e = idx >> 7, u = idx & 127;
        ip1l[e][u] = (p1d[e][u*3]*p1s[e][u*3] + p1d[e][u*3+1]*p1s[e][u*3+1]
                    + p1d[e][u*3+2]*p1s[e][u*3+2]) * (1.f/3.f);
    }
    __syncthreads();

    {
        int e = tid >> 5, h = tid & 31;
        float f = 0.f;
        for (int k = 0; k < 32; ++k) f += eal[e][k] * Wf1[k*32 + h];
        float s = sdl[e][h];
        for (int u = 0; u < 128; ++u) s += ip1l[e][u] * Ws1[(256+u)*32 + h];
        fbuf[(e0+e)*32 + h] = sspf(f);
        sbuf[(e0+e)*32 + h] = sspf(s);
    }
}

// ---------------- CSR build: count, scan, fill -----------------------------
__global__ __launch_bounds__(256) void k_count(
    const int* __restrict__ eidx, int* __restrict__ cnt)
{
    int e = blockIdx.x * 256 + threadIdx.x;
    if (e < EE){
        int d = eidx[e];
        if (d >= 0 && d < NN) atomicAdd(&cnt[d], 1);
    }
}

__global__ __launch_bounds__(256) void k_scan(
    const int* __restrict__ cnt, int* __restrict__ rowptr, int* __restrict__ cur)
{
    __shared__ int part[256];
    const int t = threadIdx.x;
    const int CHUNK = 79;             // 256*79 = 20224 >= 20000
    const int base = t * CHUNK;
    int s = 0;
    for (int i = 0; i < CHUNK; ++i){
        int idx = base + i;
        if (idx < NN) s += cnt[idx];
    }
    part[t] = s;
    __syncthreads();
    for (int off = 1; off < 256; off <<= 1){
        int v = (t >= off) ? part[t-off] : 0;
        __syncthreads();
        part[t] += v;
        __syncthreads();
    }
    int run = (t == 0) ? 0 : part[t-1];
    for (int i = 0; i < CHUNK; ++i){
        int idx = base + i;
        if (idx < NN){
            rowptr[idx] = run;
            cur[idx]    = run;
            run += cnt[idx];
        }
    }
    if (t == 255) rowptr[NN] = run;
}

__global__ __launch_bounds__(256) void k_fill(
    const int* __restrict__ eidx, int* __restrict__ cur, int2* __restrict__ ebuf,
    int* __restrict__ dstbuf)
{
    int e = blockIdx.x * 256 + threadIdx.x;
    if (e < EE){
        int dst = eidx[e];
        int src = eidx[EE + e];
        if (dst >= 0 && dst < NN){
            int pos = atomicAdd(&cur[dst], 1);
            if (pos >= 0 && pos < EE){
                ebuf[pos] = make_int2(e, src);
                dstbuf[pos] = dst;
            }
        }
    }
}

// ---------------- fused edge GEMM + segmented segment-sum ------------------
// Block = 64 CSR-ordered edges. lanes = edges; wave wv owns channel strip
// [32*wv, 32*wv+32). Weights read via wave-uniform addresses (scalar loads).
// Per-value in-wave segmented reduction (edges sorted by dst => contiguous
// lane segments); only segment-tail lanes issue atomicAdd to pre-zeroed out.
__device__ __forceinline__ void qdot(
    const float* __restrict__ W2f, const float* __restrict__ W2s,
    const float (*fbl)[33], const float (*sbl)[33],
    int lane, int q, int wv, float* wout /*32*/)
{
    float F[32], S[32];
    #pragma unroll
    for (int c = 0; c < 32; ++c){ F[c] = 0.f; S[c] = 0.f; }
    const float* wfp = W2f + q*128 + wv*32;
    const float* wsp = W2s + q*128 + wv*32;
    for (int k = 0; k < 32; ++k){
        float fb = fbl[lane][k];
        float sb = sbl[lane][k];
        const float* wf = wfp + (size_t)k*512;
        const float* ws = wsp + (size_t)k*512;
        #pragma unroll
        for (int c = 0; c < 32; ++c){
            F[c] += fb * wf[c];
            S[c] += sb * ws[c];
        }
    }
    #pragma unroll
    for (int c = 0; c < 32; ++c) wout[c] = F[c] * S[c];
}

__device__ __forceinline__ float segsum(float v, int seghead, int lane){
    #pragma unroll
    for (int o = 1; o < 64; o <<= 1){
        float t = __shfl_up(v, o);
        if (lane - o >= seghead) v += t;
    }
    return v;
}

__global__ __launch_bounds__(256) void k_edge_fused(
    const float* __restrict__ fbuf, const float* __restrict__ sbuf,
    const float* __restrict__ self_x, const float* __restrict__ esh,
    const int2* __restrict__ ebuf, const int* __restrict__ dstbuf,
    const float* __restrict__ Wf2, const float* __restrict__ Ws2,
    float* __restrict__ out)
{
    __shared__ int2  il[64];
    __shared__ int   dl[64];
    __shared__ float fbl[64][33];   // +1 pad: conflict-free lane-spread reads
    __shared__ float sbl[64][33];

    const int tid  = threadIdx.x;
    const int lane = tid & 63;
    const int wv   = __builtin_amdgcn_readfirstlane(tid >> 6); // uniform strip id
    const long e0  = (long)blockIdx.x * 64;

    if (tid < 64){
        int2 pe = ebuf[e0 + tid];
        if (!(pe.x >= 0 && pe.x < EE)) pe.x = 0;   // defensive (poison-safe)
        if (!(pe.y >= 0 && pe.y < NN)) pe.y = 0;
        int d = dstbuf[e0 + tid];
        if (!(d >= 0 && d < NN)) d = 0;
        il[tid] = pe;
        dl[tid] = d;
    }
    __syncthreads();

    for (int it = 0; it < 8; ++it){
        int idx = tid + 256*it;      // 0..2047
        int e = idx >> 5, k = idx & 31;
        int eid = il[e].x;
        fbl[e][k] = fbuf[(size_t)eid*32 + k];
        sbl[e][k] = sbuf[(size_t)eid*32 + k];
    }
    __syncthreads();

    const int eid = il[lane].x;
    const int src = il[lane].y;
    const int dst = dl[lane];
    const float4 sh = ((const float4*)esh)[eid];
    const float* sx = self_x + (size_t)src * 512;
    const float IS3 = 0.57735026919f;

    // segment geometry (identical for all 4 waves)
    int dprev = __shfl_up(dst, 1);
    unsigned long long heads = __ballot(lane == 0 || dst != dprev);
    unsigned long long below = heads & (~0ULL >> (63 - lane));
    const int seghead = 63 - __clzll(below);
    unsigned long long above = (lane < 63) ? (heads >> (lane + 1)) : 1ULL;
    const bool tail = (above & 1ULL) != 0ULL;
    float* orow = out + (size_t)dst * 512;

    float w1r[32], w4r[32];
    qdot(Wf2, Ws2, fbl, sbl, lane, 0, wv, w1r);
    qdot(Wf2, Ws2, fbl, sbl, lane, 3, wv, w4r);

    // epilogue A: out0 channels [32wv, 32wv+32), reduced per-segment
    #pragma unroll
    for (int c4 = 0; c4 < 8; ++c4){
        const int cb = wv*32 + c4*4;       // global channel base
        float4 x0 = *(const float4*)(sx + cb);
        float4 xa = *(const float4*)(sx + 128 + 3*cb);
        float4 xb = *(const float4*)(sx + 128 + 3*cb + 4);
        float4 xc = *(const float4*)(sx + 128 + 3*cb + 8);
        float d0 = xa.x*sh.y + xa.y*sh.z + xa.z*sh.w;
        float d1 = xa.w*sh.y + xb.x*sh.z + xb.y*sh.w;
        float d2 = xb.z*sh.y + xb.w*sh.z + xc.x*sh.w;
        float d3 = xc.y*sh.y + xc.z*sh.z + xc.w*sh.w;
        int i0 = c4*4;
        float o0 = w1r[i0+0]*x0.x*sh.x + w4r[i0+0]*d0*IS3;
        float o1 = w1r[i0+1]*x0.y*sh.x + w4r[i0+1]*d1*IS3;
        float o2 = w1r[i0+2]*x0.z*sh.x + w4r[i0+2]*d2*IS3;
        float o3 = w1r[i0+3]*x0.w*sh.x + w4r[i0+3]*d3*IS3;
        o0 = segsum(o0, seghead, lane);
        o1 = segsum(o1, seghead, lane);
        o2 = segsum(o2, seghead, lane);
        o3 = segsum(o3, seghead, lane);
        if (tail){
            atomicAdd(orow + cb + 0, o0);
            atomicAdd(orow + cb + 1, o1);
            atomicAdd(orow + cb + 2, o2);
            atomicAdd(orow + cb + 3, o3);
        }
    }

    float w2r[32], w3r[32];
    qdot(Wf2, Ws2, fbl, sbl, lane, 1, wv, w2r);
    qdot(Wf2, Ws2, fbl, sbl, lane, 2, wv, w3r);

    // epilogue B: out1 channels -> positions 128+3c+m, reduced per-segment
    #pragma unroll
    for (int c4 = 0; c4 < 8; ++c4){
        const int cb = wv*32 + c4*4;
        float4 x0 = *(const float4*)(sx + cb);
        float4 xa = *(const float4*)(sx + 128 + 3*cb);
        float4 xb = *(const float4*)(sx + 128 + 3*cb + 4);
        float4 xc = *(const float4*)(sx + 128 + 3*cb + 8);
        int i0 = c4*4;
        float t0 = w2r[i0+0]*x0.x, g0 = w3r[i0+0]*sh.x;
        float t1 = w2r[i0+1]*x0.y, g1 = w3r[i0+1]*sh.x;
        float t2 = w2r[i0+2]*x0.z, g2 = w3r[i0+2]*sh.x;
        float t3 = w2r[i0+3]*x0.w, g3 = w3r[i0+3]*sh.x;
        float m[12];
        m[0]  = t0*sh.y + g0*xa.x; m[1]  = t0*sh.z + g0*xa.y; m[2]  = t0*sh.w + g0*xa.z;
        m[3]  = t1*sh.y + g1*xa.w; m[4]  = t1*sh.z + g1*xb.x; m[5]  = t1*sh.w + g1*xb.y;
        m[6]  = t2*sh.y + g2*xb.z; m[7]  = t2*sh.z + g2*xb.w; m[8]  = t2*sh.w + g2*xc.x;
        m[9]  = t3*sh.y + g3*xc.y; m[10] = t3*sh.z + g3*xc.z; m[11] = t3*sh.w + g3*xc.w;
        #pragma unroll
        for (int i = 0; i < 12; ++i) m[i] = segsum(m[i], seghead, lane);
        if (tail){
            #pragma unroll
            for (int i = 0; i < 12; ++i) atomicAdd(orow + 128 + 3*cb + i, m[i]);
        }
    }
}

// ---------------- K5: out linear + residual (in-place over d_out) ----------
__global__ __launch_bounds__(256) void k_post(
    const float* __restrict__ self_x, const float* __restrict__ x,
    const float* __restrict__ Wo0, const float* __restrict__ bo0,
    const float* __restrict__ Wo1,
    float* __restrict__ out)
{
    __shared__ float tl[512][8];
    const int tid = threadIdx.x;
    const int n0 = blockIdx.x * 8;

    for (int it = 0; it < 4; ++it){
        int idx = tid + 256*it;
        int node = idx >> 7, o4 = idx & 127;
        float4 a = ((const float4*)(out    + (size_t)(n0+node)*512))[o4];
        float4 b = ((const float4*)(self_x + (size_t)(n0+node)*512))[o4];
        tl[o4*4+0][node]=a.x+b.x; tl[o4*4+1][node]=a.y+b.y;
        tl[o4*4+2][node]=a.z+b.z; tl[o4*4+3][node]=a.w+b.w;
    }
    __syncthreads();

    const int j = tid;
    float acc1[8] = {0,0,0,0,0,0,0,0};
    float acc2[8] = {0,0,0,0,0,0,0,0};
    const int o2 = j + 128;
    const int v2 = o2/3, m2 = o2%3;
    if (j < 128){
        for (int u = 0; u < 128; ++u){
            float w1 = Wo0[u*128 + j];
            float w2 = Wo1[u*128 + v2];
            fma8(acc1, &tl[u][0], w1);
            fma8(acc2, &tl[128 + u*3 + m2][0], w2);
        }
        float b = bo0[j];
        #pragma unroll
        for (int n = 0; n < 8; ++n)
            out[(size_t)(n0+n)*512 + j] = acc1[n] + b + x[(size_t)(n0+n)*512 + j];
    } else {
        const int o1 = j - 128, v1 = o1/3, m1 = o1%3;
        for (int u = 0; u < 128; ++u){
            float w1 = Wo1[u*128 + v1];
            float w2 = Wo1[u*128 + v2];
            fma8(acc1, &tl[128 + u*3 + m1][0], w1);
            fma8(acc2, &tl[128 + u*3 + m2][0], w2);
        }
        #pragma unroll
        for (int n = 0; n < 8; ++n)
            out[(size_t)(n0+n)*512 + j] = acc1[n] + x[(size_t)(n0+n)*512 + j];
    }
    #pragma unroll
    for (int n = 0; n < 8; ++n)
        out[(size_t)(n0+n)*512 + j + 256] = acc2[n] + x[(size_t)(n0+n)*512 + j + 256];
}

// ---------------------------------------------------------------------------
extern "C" void kernel_launch(void* const* d_in, const int* in_sizes, int n_in,
                              void* d_out, int out_size, void* d_ws, size_t ws_size,
                              hipStream_t stream)
{
    const float* x    = (const float*)d_in[0];
    const float* esh  = (const float*)d_in[1];
    const float* ea   = (const float*)d_in[2];
    const int*   eidx = (const int*)  d_in[3];
    const float* Wp0  = (const float*)d_in[4];
    const float* bp0  = (const float*)d_in[5];
    const float* Wp1  = (const float*)d_in[6];
    const float* Wnd0 = (const float*)d_in[7];
    const float* bnd0 = (const float*)d_in[8];
    const float* Wnd1 = (const float*)d_in[9];
    const float* Wg1  = (const float*)d_in[10];
    const float* bg1  = (const float*)d_in[11];
    const float* Wg2  = (const float*)d_in[12];
    const float* bg2  = (const float*)d_in[13];
    const float* Wf1  = (const float*)d_in[14];
    const float* Wf2  = (const float*)d_in[15];
    const float* Ws1  = (const float*)d_in[16];
    const float* Ws2  = (const float*)d_in[17];
    const float* Wo0  = (const float*)d_in[18];
    const float* bo0  = (const float*)d_in[19];
    const float* Wo1  = (const float*)d_in[20];

    float* out  = (float*)d_out;
    float* ws   = (float*)d_ws;
    float* p1   = ws;                              // N*384 (dead after k_edge_pre)
    float* sdst = p1   + (size_t)NN*384;           // N*32
    float* sfx  = sdst + (size_t)NN*32;            // N*512
    float* fbuf = sfx  + (size_t)NN*512;           // E*32
    float* sbuf = fbuf + (size_t)EE*32;            // E*32

    // CSR arrays overlay the dead p1 region (~2.6 MB << 30 MB)
    int*  cnt    = (int*)p1;
    int*  rowptr = cnt + NN;            // N+1
    int*  cur    = rowptr + NN + 1;     // N
    int2* ebuf   = (int2*)(cur + NN + 1);   // E int2 (byte offset 240008, 8-aligned)
    int*  dstbuf = (int*)(ebuf + EE);       // E int

    k_pre     <<<NN/8, 256, 0, stream>>>(x, Wp0, bp0, Wp1, Ws1, p1, sdst);
    k_gate_nd <<<NN/8, 256, 0, stream>>>(x, Wg1, bg1, Wg2, bg2, Wnd0, bnd0, Wnd1, sfx);
    k_edge_pre<<<EE/8, 256, 0, stream>>>(p1, sdst, ea, eidx, Wf1, Ws1, fbuf, sbuf);

    // p1 is now dead — build CSR in its place
    hipMemsetAsync(cnt, 0, (size_t)NN*sizeof(int), stream);
    k_count <<<(EE+255)/256, 256, 0, stream>>>(eidx, cnt);
    k_scan  <<<1, 256, 0, stream>>>(cnt, rowptr, cur);
    k_fill  <<<(EE+255)/256, 256, 0, stream>>>(eidx, cur, ebuf, dstbuf);

    // zero out, then fused edge GEMM + segmented segment-sum (atomics)
    hipMemsetAsync(out, 0, (size_t)NN*512*sizeof(float), stream);
    k_edge_fused<<<EE/64, 256, 0, stream>>>(fbuf, sbuf, sfx, esh, ebuf, dstbuf,
                                            Wf2, Ws2, out);

    k_post    <<<NN/8, 256, 0, stream>>>(sfx, x, Wo0, bo0, Wo1, out);
}

// Round 2
// 1441.342 us; speedup vs baseline: 1.0623x; 1.0623x over previous
//
#include <hip/hip_runtime.h>
#include <hip/hip_fp16.h>
#include <math.h>

#define NN 20000
#define EE 200000
// MUL=128, D=512, EDGE_ATTR=32, HID=32

__device__ __forceinline__ float sspf(float x){
    float sp = (x > 20.f) ? x : log1pf(expf(x));
    return sp - 0.69314718056f;
}

__device__ __forceinline__ void fma8(float* acc, const float* base, float w){
    const float4 a = ((const float4*)base)[0];
    const float4 b = ((const float4*)base)[1];
    acc[0]+=a.x*w; acc[1]+=a.y*w; acc[2]+=a.z*w; acc[3]+=a.w*w;
    acc[4]+=b.x*w; acc[5]+=b.y*w; acc[6]+=b.z*w; acc[7]+=b.w*w;
}

// ---------------- K1: pre irrep_linear -> p1, sdst (p0 consumed in-LDS) ----
__global__ __launch_bounds__(256) void k_pre(
    const float* __restrict__ x, const float* __restrict__ Wp0,
    const float* __restrict__ bp0, const float* __restrict__ Wp1,
    const float* __restrict__ Ws1,
    float* __restrict__ p1, float* __restrict__ sdst)
{
    __shared__ float xl[512][8];    // transposed [feature][node]
    __shared__ float p0l[8][128];
    const int tid = threadIdx.x;
    const int n0 = blockIdx.x * 8;

    for (int it = 0; it < 4; ++it){
        int idx = tid + 256*it;           // 0..1023 float4 slots
        int node = idx >> 7, o4 = idx & 127;
        float4 v = ((const float4*)(x + (size_t)(n0+node)*512))[o4];
        xl[o4*4+0][node]=v.x; xl[o4*4+1][node]=v.y;
        xl[o4*4+2][node]=v.z; xl[o4*4+3][node]=v.w;
    }
    __syncthreads();

    const int j = tid;
    float acc1[8] = {0,0,0,0,0,0,0,0};
    float acc2[8] = {0,0,0,0,0,0,0,0};
    const int o2 = j + 128;               // p1-index in [128,384)
    const int v2 = o2/3, m2 = o2%3;

    if (j < 128){
        for (int u = 0; u < 128; ++u){
            float w1 = Wp0[u*128 + j];
            float w2 = Wp1[u*128 + v2];
            fma8(acc1, &xl[u][0], w1);
            fma8(acc2, &xl[128 + u*3 + m2][0], w2);
        }
        float b = bp0[j];
        #pragma unroll
        for (int n = 0; n < 8; ++n) p0l[n][j] = acc1[n] + b;
    } else {
        const int o1 = j - 128, v1 = o1/3, m1 = o1%3;
        for (int u = 0; u < 128; ++u){
            float w1 = Wp1[u*128 + v1];
            float w2 = Wp1[u*128 + v2];
            fma8(acc1, &xl[128 + u*3 + m1][0], w1);
            fma8(acc2, &xl[128 + u*3 + m2][0], w2);
        }
        #pragma unroll
        for (int n = 0; n < 8; ++n) p1[(size_t)(n0+n)*384 + (j-128)] = acc1[n];
    }
    #pragma unroll
    for (int n = 0; n < 8; ++n) p1[(size_t)(n0+n)*384 + o2] = acc2[n];
    __syncthreads();

    // sdst = p0 @ (Ws1[0:128] + Ws1[128:256])  (the dst-only part of s0@W_s1)
    {
        int n = tid >> 5, h = tid & 31;
        float s = 0.f;
        for (int u = 0; u < 128; ++u){
            float wc = Ws1[u*32 + h] + Ws1[(128+u)*32 + h];
            s += p0l[n][u] * wc;
        }
        sdst[(size_t)(n0+n)*32 + h] = s;
    }
}

// ---------------- K2: gate + node irrep_linear -> self_x -------------------
__global__ __launch_bounds__(256) void k_gate_nd(
    const float* __restrict__ x,
    const float* __restrict__ Wg1, const float* __restrict__ bg1,
    const float* __restrict__ Wg2, const float* __restrict__ bg2,
    const float* __restrict__ Wnd0, const float* __restrict__ bnd0,
    const float* __restrict__ Wnd1,
    float* __restrict__ self_x)
{
    __shared__ float xl[512][8];
    __shared__ float tl[256][8];   // t, then reused for g
    __shared__ float hl[256][8];
    const int tid = threadIdx.x;
    const int n0 = blockIdx.x * 8;

    for (int it = 0; it < 4; ++it){
        int idx = tid + 256*it;
        int node = idx >> 7, o4 = idx & 127;
        float4 v = ((const float4*)(x + (size_t)(n0+node)*512))[o4];
        xl[o4*4+0][node]=v.x; xl[o4*4+1][node]=v.y;
        xl[o4*4+2][node]=v.z; xl[o4*4+3][node]=v.w;
    }
    __syncthreads();

    { // t = [x0, n1]
        int jj = tid;
        if (jj < 128){
            #pragma unroll
            for (int n = 0; n < 8; ++n) tl[jj][n] = xl[jj][n];
        } else {
            int u = jj - 128;
            #pragma unroll
            for (int n = 0; n < 8; ++n){
                float a = xl[128+u*3][n], b = xl[128+u*3+1][n], c = xl[128+u*3+2][n];
                tl[jj][n] = sqrtf((a*a + b*b + c*c) * (1.f/3.f));
            }
        }
    }
    __syncthreads();

    { // h = silu(t @ Wg1 + bg1)
        float acc[8] = {0,0,0,0,0,0,0,0};
        for (int k = 0; k < 256; ++k){
            float w = Wg1[k*256 + tid];
            fma8(acc, &tl[k][0], w);
        }
        float b = bg1[tid];
        #pragma unroll
        for (int n = 0; n < 8; ++n){
            float v = acc[n] + b;
            hl[tid][n] = v / (1.f + expf(-v));
        }
    }
    __syncthreads();

    { // g = h @ Wg2 + bg2  (stored into tl; tl is dead after the barrier)
        float acc[8] = {0,0,0,0,0,0,0,0};
        for (int k = 0; k < 256; ++k){
            float w = Wg2[k*256 + tid];
            fma8(acc, &hl[k][0], w);
        }
        float b = bg2[tid];
        #pragma unroll
        for (int n = 0; n < 8; ++n) tl[tid][n] = acc[n] + b;
    }
    __syncthreads();

    { // xg in-place into xl
        int jj = tid;
        if (jj < 128){
            #pragma unroll
            for (int n = 0; n < 8; ++n) xl[jj][n] = tl[jj][n];
        } else {
            int u = jj - 128;
            #pragma unroll
            for (int n = 0; n < 8; ++n){
                float g1 = tl[128+u][n];
                xl[128+u*3  ][n] *= g1;
                xl[128+u*3+1][n] *= g1;
                xl[128+u*3+2][n] *= g1;
            }
        }
    }
    __syncthreads();

    // nd irrep_linear
    const int j = tid;
    float acc1[8] = {0,0,0,0,0,0,0,0};
    float acc2[8] = {0,0,0,0,0,0,0,0};
    const int o2 = j + 128;
    const int v2 = o2/3, m2 = o2%3;
    if (j < 128){
        for (int u = 0; u < 128; ++u){
            float w1 = Wnd0[u*128 + j];
            float w2 = Wnd1[u*128 + v2];
            fma8(acc1, &xl[u][0], w1);
            fma8(acc2, &xl[128 + u*3 + m2][0], w2);
        }
        float b = bnd0[j];
        #pragma unroll
        for (int n = 0; n < 8; ++n) self_x[(size_t)(n0+n)*512 + j] = acc1[n] + b;
    } else {
        const int o1 = j - 128, v1 = o1/3, m1 = o1%3;
        for (int u = 0; u < 128; ++u){
            float w1 = Wnd1[u*128 + v1];
            float w2 = Wnd1[u*128 + v2];
            fma8(acc1, &xl[128 + u*3 + m1][0], w1);
            fma8(acc2, &xl[128 + u*3 + m2][0], w2);
        }
        #pragma unroll
        for (int n = 0; n < 8; ++n) self_x[(size_t)(n0+n)*512 + j] = acc1[n];
    }
    #pragma unroll
    for (int n = 0; n < 8; ++n) self_x[(size_t)(n0+n)*512 + j + 256] = acc2[n];
}

// ---------------- K3: edge features -> fbuf, sbuf (E x 32 each) ------------
__global__ __launch_bounds__(256) void k_edge_pre(
    const float* __restrict__ p1g, const float* __restrict__ sdst,
    const float* __restrict__ ea, const int* __restrict__ eidx,
    const float* __restrict__ Wf1, const float* __restrict__ Ws1,
    float* __restrict__ fbuf, float* __restrict__ sbuf)
{
    __shared__ float p1d[8][384], p1s[8][384];
    __shared__ float eal[8][32], sdl[8][32];
    __shared__ float ip1l[8][128];
    __shared__ int il[8][2];
    const int tid = threadIdx.x;
    const long e0 = (long)blockIdx.x * 8;

    if (tid < 16){
        int e = tid & 7;
        il[e][tid>>3] = eidx[(size_t)(tid>>3)*EE + e0 + e];
    }
    __syncthreads();

    for (int e = 0; e < 8; ++e){
        int dst = il[e][0], src = il[e][1];
        if (tid < 96)
            ((float4*)p1d[e])[tid] = ((const float4*)(p1g + (size_t)dst*384))[tid];
        else if (tid < 192)
            ((float4*)p1s[e])[tid-96] = ((const float4*)(p1g + (size_t)src*384))[tid-96];
        else if (tid < 200)
            ((float4*)eal[e])[tid-192] = ((const float4*)(ea + (e0+e)*32))[tid-192];
        else if (tid < 208)
            ((float4*)sdl[e])[tid-200] = ((const float4*)(sdst + (size_t)dst*32))[tid-200];
    }
    __syncthreads();

    for (int it = 0; it < 4; ++it){
        int idx = tid + 256*it;
        int e = idx >> 7, u = idx & 127;
        ip1l[e][u] = (p1d[e][u*3]*p1s[e][u*3] + p1d[e][u*3+1]*p1s[e][u*3+1]
                    + p1d[e][u*3+2]*p1s[e][u*3+2]) * (1.f/3.f);
    }
    __syncthreads();

    {
        int e = tid >> 5, h = tid & 31;
        float f = 0.f;
        for (int k = 0; k < 32; ++k) f += eal[e][k] * Wf1[k*32 + h];
        float s = sdl[e][h];
        for (int u = 0; u < 128; ++u) s += ip1l[e][u] * Ws1[(256+u)*32 + h];
        fbuf[(e0+e)*32 + h] = sspf(f);
        sbuf[(e0+e)*32 + h] = sspf(s);
    }
}

// ---------------- CSR build: count, scan, fill -----------------------------
__global__ __launch_bounds__(256) void k_count(
    const int* __restrict__ eidx, int* __restrict__ cnt)
{
    int e = blockIdx.x * 256 + threadIdx.x;
    if (e < EE){
        int d = eidx[e];
        if (d >= 0 && d < NN) atomicAdd(&cnt[d], 1);
    }
}

__global__ __launch_bounds__(256) void k_scan(
    const int* __restrict__ cnt, int* __restrict__ rowptr, int* __restrict__ cur)
{
    __shared__ int part[256];
    const int t = threadIdx.x;
    const int CHUNK = 79;             // 256*79 = 20224 >= 20000
    const int base = t * CHUNK;
    int s = 0;
    for (int i = 0; i < CHUNK; ++i){
        int idx = base + i;
        if (idx < NN) s += cnt[idx];
    }
    part[t] = s;
    __syncthreads();
    for (int off = 1; off < 256; off <<= 1){
        int v = (t >= off) ? part[t-off] : 0;
        __syncthreads();
        part[t] += v;
        __syncthreads();
    }
    int run = (t == 0) ? 0 : part[t-1];
    for (int i = 0; i < CHUNK; ++i){
        int idx = base + i;
        if (idx < NN){
            rowptr[idx] = run;
            cur[idx]    = run;
            run += cnt[idx];
        }
    }
    if (t == 255) rowptr[NN] = run;
}

__global__ __launch_bounds__(256) void k_fill(
    const int* __restrict__ eidx, int* __restrict__ cur, int2* __restrict__ ebuf)
{
    int e = blockIdx.x * 256 + threadIdx.x;
    if (e < EE){
        int dst = eidx[e];
        int src = eidx[EE + e];
        if (dst >= 0 && dst < NN){
            int pos = atomicAdd(&cur[dst], 1);
            if (pos >= 0 && pos < EE) ebuf[pos] = make_int2(e, src);
        }
    }
}

// ---------------- edge GEMM -> fp32 edge_feat chunk ------------------------
// Block = 64 CSR-ordered edges (positions [e0,e0+64)). lanes = edges; wave wv
// owns channel strip [32wv,32wv+32). Per-c4 restructure: both epilogues merged
// (sx read once), weights via wave-uniform scalar loads, coalesced fp32 ef
// writes, no shuffles, no atomics.
__global__ __launch_bounds__(256) void k_w_edge2(
    const float* __restrict__ fbuf, const float* __restrict__ sbuf,
    const float* __restrict__ self_x, const float* __restrict__ esh,
    const int2* __restrict__ ebuf,
    const float* __restrict__ Wf2, const float* __restrict__ Ws2,
    float* __restrict__ ef, int c0)
{
    __shared__ int2  il[64];
    __shared__ float fbl[64][36];   // pad 36: b128-aligned, conflict-free
    __shared__ float sbl[64][36];

    const int tid  = threadIdx.x;
    const int lane = tid & 63;
    const int wv   = __builtin_amdgcn_readfirstlane(tid >> 6); // uniform strip id
    const int e0   = c0 + blockIdx.x * 64;

    if (tid < 64){
        int2 pe = ebuf[(size_t)e0 + tid];
        if (!(pe.x >= 0 && pe.x < EE)) pe.x = 0;   // defensive (poison-safe)
        if (!(pe.y >= 0 && pe.y < NN)) pe.y = 0;
        il[tid] = pe;
    }
    __syncthreads();

    for (int it = 0; it < 8; ++it){
        int idx = tid + 256*it;      // 0..2047
        int e = idx >> 5, k = idx & 31;
        int eid = il[e].x;
        fbl[e][k] = fbuf[(size_t)eid*32 + k];
        sbl[e][k] = sbuf[(size_t)eid*32 + k];
    }
    __syncthreads();

    const int eid = il[lane].x;
    const int src = il[lane].y;
    const float4 sh = ((const float4*)esh)[eid];
    const float* sx = self_x + (size_t)src * 512;
    float* efr = ef + (size_t)(e0 - c0 + lane) * 512;
    const float IS3 = 0.57735026919f;

    #pragma unroll
    for (int c4 = 0; c4 < 8; ++c4){
        const int cb = wv*32 + c4*4;       // global channel base
        float F[4][4], S[4][4];
        #pragma unroll
        for (int q = 0; q < 4; ++q)
            #pragma unroll
            for (int c = 0; c < 4; ++c){ F[q][c] = 0.f; S[q][c] = 0.f; }

        for (int kb = 0; kb < 8; ++kb){
            float4 fb4 = *(const float4*)&fbl[lane][kb*4];
            float4 sb4 = *(const float4*)&sbl[lane][kb*4];
            const float fbs[4] = {fb4.x, fb4.y, fb4.z, fb4.w};
            const float sbs[4] = {sb4.x, sb4.y, sb4.z, sb4.w};
            #pragma unroll
            for (int kk = 0; kk < 4; ++kk){
                const int k = kb*4 + kk;
                #pragma unroll
                for (int q = 0; q < 4; ++q){
                    const float4 wf = *(const float4*)(Wf2 + (size_t)k*512 + q*128 + cb);
                    const float4 ws = *(const float4*)(Ws2 + (size_t)k*512 + q*128 + cb);
                    F[q][0] += fbs[kk]*wf.x; F[q][1] += fbs[kk]*wf.y;
                    F[q][2] += fbs[kk]*wf.z; F[q][3] += fbs[kk]*wf.w;
                    S[q][0] += sbs[kk]*ws.x; S[q][1] += sbs[kk]*ws.y;
                    S[q][2] += sbs[kk]*ws.z; S[q][3] += sbs[kk]*ws.w;
                }
            }
        }

        float w1[4], w2[4], w3[4], w4[4];
        #pragma unroll
        for (int c = 0; c < 4; ++c){
            w1[c] = F[0][c]*S[0][c];
            w2[c] = F[1][c]*S[1][c];
            w3[c] = F[2][c]*S[2][c];
            w4[c] = F[3][c]*S[3][c];
        }

        // merged epilogue: sx slice read once
        float4 x0 = *(const float4*)(sx + cb);
        float4 xa = *(const float4*)(sx + 128 + 3*cb);
        float4 xb = *(const float4*)(sx + 128 + 3*cb + 4);
        float4 xc = *(const float4*)(sx + 128 + 3*cb + 8);

        // out0
        float d0 = xa.x*sh.y + xa.y*sh.z + xa.z*sh.w;
        float d1 = xa.w*sh.y + xb.x*sh.z + xb.y*sh.w;
        float d2 = xb.z*sh.y + xb.w*sh.z + xc.x*sh.w;
        float d3 = xc.y*sh.y + xc.z*sh.z + xc.w*sh.w;
        float o0 = w1[0]*x0.x*sh.x + w4[0]*d0*IS3;
        float o1 = w1[1]*x0.y*sh.x + w4[1]*d1*IS3;
        float o2 = w1[2]*x0.z*sh.x + w4[2]*d2*IS3;
        float o3 = w1[3]*x0.w*sh.x + w4[3]*d3*IS3;
        *(float4*)(efr + cb) = make_float4(o0, o1, o2, o3);

        // out1 -> positions 128+3c+m
        float t0 = w2[0]*x0.x, g0 = w3[0]*sh.x;
        float t1 = w2[1]*x0.y, g1 = w3[1]*sh.x;
        float t2 = w2[2]*x0.z, g2 = w3[2]*sh.x;
        float t3 = w2[3]*x0.w, g3 = w3[3]*sh.x;
        float m00 = t0*sh.y + g0*xa.x, m01 = t0*sh.z + g0*xa.y, m02 = t0*sh.w + g0*xa.z;
        float m10 = t1*sh.y + g1*xa.w, m11 = t1*sh.z + g1*xb.x, m12 = t1*sh.w + g1*xb.y;
        float m20 = t2*sh.y + g2*xb.z, m21 = t2*sh.z + g2*xb.w, m22 = t2*sh.w + g2*xc.x;
        float m30 = t3*sh.y + g3*xc.y, m31 = t3*sh.z + g3*xc.z, m32 = t3*sh.w + g3*xc.w;
        float* eb = efr + 128 + 3*cb;
        *(float4*)(eb)     = make_float4(m00, m01, m02, m10);
        *(float4*)(eb + 4) = make_float4(m11, m12, m20, m21);
        *(float4*)(eb + 8) = make_float4(m22, m30, m31, m32);
    }
}

// ---------------- coalesced CSR segment sum (accumulating, chunked) --------
__global__ __launch_bounds__(256) void k_seg_sum(
    const float* __restrict__ ef, const int* __restrict__ rowptr,
    int c0, int c1, float* __restrict__ out)
{
    const int tid  = threadIdx.x;
    const int lane = tid & 63;
    const int n    = blockIdx.x * 4 + (tid >> 6);
    const int s0   = rowptr[n];
    const int e1   = rowptr[n+1];
    int start = (s0 < c0) ? c0 : s0;
    int end   = (e1 > c1) ? c1 : e1;
    if (start >= end) return;          // wave-uniform exit (n is per-wave)
    if (start < 0)  start = 0;
    if (end > EE)   end = EE;

    float a[8] = {0,0,0,0,0,0,0,0};
    float* op = out + (size_t)n*512 + lane*8;
    if (s0 < c0){                      // continuation: accumulate onto prior chunks
        float4 r0 = *(const float4*)op;
        float4 r1 = *((const float4*)op + 1);
        a[0]=r0.x; a[1]=r0.y; a[2]=r0.z; a[3]=r0.w;
        a[4]=r1.x; a[5]=r1.y; a[6]=r1.z; a[7]=r1.w;
    }
    for (int i = start; i < end; ++i){
        const float* ep = ef + (size_t)(i - c0)*512 + lane*8;
        float4 r0 = *(const float4*)ep;
        float4 r1 = *((const float4*)ep + 1);
        a[0]+=r0.x; a[1]+=r0.y; a[2]+=r0.z; a[3]+=r0.w;
        a[4]+=r1.x; a[5]+=r1.y; a[6]+=r1.z; a[7]+=r1.w;
    }
    *(float4*)op       = make_float4(a[0], a[1], a[2], a[3]);
    *((float4*)op + 1) = make_float4(a[4], a[5], a[6], a[7]);
}

// ---------------- K5: out linear + residual (in-place over d_out) ----------
__global__ __launch_bounds__(256) void k_post(
    const float* __restrict__ self_x, const float* __restrict__ x,
    const float* __restrict__ Wo0, const float* __restrict__ bo0,
    const float* __restrict__ Wo1,
    float* __restrict__ out)
{
    __shared__ float tl[512][8];
    const int tid = threadIdx.x;
    const int n0 = blockIdx.x * 8;

    for (int it = 0; it < 4; ++it){
        int idx = tid + 256*it;
        int node = idx >> 7, o4 = idx & 127;
        float4 a = ((const float4*)(out    + (size_t)(n0+node)*512))[o4];
        float4 b = ((const float4*)(self_x + (size_t)(n0+node)*512))[o4];
        tl[o4*4+0][node]=a.x+b.x; tl[o4*4+1][node]=a.y+b.y;
        tl[o4*4+2][node]=a.z+b.z; tl[o4*4+3][node]=a.w+b.w;
    }
    __syncthreads();

    const int j = tid;
    float acc1[8] = {0,0,0,0,0,0,0,0};
    float acc2[8] = {0,0,0,0,0,0,0,0};
    const int o2 = j + 128;
    const int v2 = o2/3, m2 = o2%3;
    if (j < 128){
        for (int u = 0; u < 128; ++u){
            float w1 = Wo0[u*128 + j];
            float w2 = Wo1[u*128 + v2];
            fma8(acc1, &tl[u][0], w1);
            fma8(acc2, &tl[128 + u*3 + m2][0], w2);
        }
        float b = bo0[j];
        #pragma unroll
        for (int n = 0; n < 8; ++n)
            out[(size_t)(n0+n)*512 + j] = acc1[n] + b + x[(size_t)(n0+n)*512 + j];
    } else {
        const int o1 = j - 128, v1 = o1/3, m1 = o1%3;
        for (int u = 0; u < 128; ++u){
            float w1 = Wo1[u*128 + v1];
            float w2 = Wo1[u*128 + v2];
            fma8(acc1, &tl[128 + u*3 + m1][0], w1);
            fma8(acc2, &tl[128 + u*3 + m2][0], w2);
        }
        #pragma unroll
        for (int n = 0; n < 8; ++n)
            out[(size_t)(n0+n)*512 + j] = acc1[n] + x[(size_t)(n0+n)*512 + j];
    }
    #pragma unroll
    for (int n = 0; n < 8; ++n)
        out[(size_t)(n0+n)*512 + j + 256] = acc2[n] + x[(size_t)(n0+n)*512 + j + 256];
}

// ---------------------------------------------------------------------------
extern "C" void kernel_launch(void* const* d_in, const int* in_sizes, int n_in,
                              void* d_out, int out_size, void* d_ws, size_t ws_size,
                              hipStream_t stream)
{
    const float* x    = (const float*)d_in[0];
    const float* esh  = (const float*)d_in[1];
    const float* ea   = (const float*)d_in[2];
    const int*   eidx = (const int*)  d_in[3];
    const float* Wp0  = (const float*)d_in[4];
    const float* bp0  = (const float*)d_in[5];
    const float* Wp1  = (const float*)d_in[6];
    const float* Wnd0 = (const float*)d_in[7];
    const float* bnd0 = (const float*)d_in[8];
    const float* Wnd1 = (const float*)d_in[9];
    const float* Wg1  = (const float*)d_in[10];
    const float* bg1  = (const float*)d_in[11];
    const float* Wg2  = (const float*)d_in[12];
    const float* bg2  = (const float*)d_in[13];
    const float* Wf1  = (const float*)d_in[14];
    const float* Wf2  = (const float*)d_in[15];
    const float* Ws1  = (const float*)d_in[16];
    const float* Ws2  = (const float*)d_in[17];
    const float* Wo0  = (const float*)d_in[18];
    const float* bo0  = (const float*)d_in[19];
    const float* Wo1  = (const float*)d_in[20];

    float* out  = (float*)d_out;
    float* ws   = (float*)d_ws;
    float* p1   = ws;                              // N*384 (dead after k_edge_pre)
    float* sdst = p1   + (size_t)NN*384;           // N*32
    float* sfx  = sdst + (size_t)NN*32;            // N*512
    float* fbuf = sfx  + (size_t)NN*512;           // E*32
    float* sbuf = fbuf + (size_t)EE*32;            // E*32

    // CSR arrays overlay the dead p1 region
    int*  cnt    = (int*)p1;
    int*  rowptr = cnt + NN;            // N+1
    int*  cur    = rowptr + NN + 1;     // N
    int2* ebuf   = (int2*)(cur + NN + 1);   // E int2 (byte off 240008, 8-aligned)

    k_pre     <<<NN/8, 256, 0, stream>>>(x, Wp0, bp0, Wp1, Ws1, p1, sdst);
    k_gate_nd <<<NN/8, 256, 0, stream>>>(x, Wg1, bg1, Wg2, bg2, Wnd0, bnd0, Wnd1, sfx);
    k_edge_pre<<<EE/8, 256, 0, stream>>>(p1, sdst, ea, eidx, Wf1, Ws1, fbuf, sbuf);

    // p1 is now dead — build CSR in its place
    hipMemsetAsync(cnt, 0, (size_t)NN*sizeof(int), stream);
    k_count <<<(EE+255)/256, 256, 0, stream>>>(eidx, cnt);
    k_scan  <<<1, 256, 0, stream>>>(cnt, rowptr, cur);
    k_fill  <<<(EE+255)/256, 256, 0, stream>>>(eidx, cur, ebuf);

    hipMemsetAsync(out, 0, (size_t)NN*512*sizeof(float), stream);

    // fp32 edge_feat chunk: prefer dedicated ws region (adaptive size); else
    // overlay the remainder of the dead p1 region (guaranteed to exist).
    const size_t base  = (size_t)NN*928*4 + (size_t)EE*64*4;   // 125.44 MB in use
    const size_t avail = (ws_size > base) ? (ws_size - base) : 0;
    long   chunk;
    float* efx;
    if (avail >= (size_t)25600*2048){           // >= 25600-edge chunk dedicated
        long c = (long)(avail / 2048) & ~63L;
        chunk = (c > EE) ? EE : c;
        efx   = (float*)((char*)ws + base);
    } else {
        // p1 region: CSR ends at byte 240008 + E*8 = 1,840,008; align 16
        chunk = 12800;                           // 12800*2048 B = 26.2 MB
        efx   = (float*)((char*)ws + 1840016);
    }

    for (long c0 = 0; c0 < EE; c0 += chunk){
        long c1 = c0 + chunk; if (c1 > EE) c1 = EE;
        k_w_edge2<<<(int)((c1-c0)/64), 256, 0, stream>>>(
            fbuf, sbuf, sfx, esh, ebuf, Wf2, Ws2, efx, (int)c0);
        k_seg_sum<<<NN/4, 256, 0, stream>>>(efx, rowptr, (int)c0, (int)c1, out);
    }

    k_post    <<<NN/8, 256, 0, stream>>>(sfx, x, Wo0, bo0, Wo1, out);
}

// Round 3
// 1035.520 us; speedup vs baseline: 1.4786x; 1.3919x over previous
//
#include <hip/hip_runtime.h>
#include <hip/hip_fp16.h>
#include <math.h>

#define NN 20000
#define EE 200000
// MUL=128, D=512, EDGE_ATTR=32, HID=32

__device__ __forceinline__ float sspf(float x){
    float sp = (x > 20.f) ? x : log1pf(expf(x));
    return sp - 0.69314718056f;
}

__device__ __forceinline__ void fma8(float* acc, const float* base, float w){
    const float4 a = ((const float4*)base)[0];
    const float4 b = ((const float4*)base)[1];
    acc[0]+=a.x*w; acc[1]+=a.y*w; acc[2]+=a.z*w; acc[3]+=a.w*w;
    acc[4]+=b.x*w; acc[5]+=b.y*w; acc[6]+=b.z*w; acc[7]+=b.w*w;
}

// ---------------- K1: pre irrep_linear -> p1, sdst (p0 consumed in-LDS) ----
__global__ __launch_bounds__(256) void k_pre(
    const float* __restrict__ x, const float* __restrict__ Wp0,
    const float* __restrict__ bp0, const float* __restrict__ Wp1,
    const float* __restrict__ Ws1,
    float* __restrict__ p1, float* __restrict__ sdst)
{
    __shared__ float xl[512][8];    // transposed [feature][node]
    __shared__ float p0l[8][128];
    const int tid = threadIdx.x;
    const int n0 = blockIdx.x * 8;

    for (int it = 0; it < 4; ++it){
        int idx = tid + 256*it;           // 0..1023 float4 slots
        int node = idx >> 7, o4 = idx & 127;
        float4 v = ((const float4*)(x + (size_t)(n0+node)*512))[o4];
        xl[o4*4+0][node]=v.x; xl[o4*4+1][node]=v.y;
        xl[o4*4+2][node]=v.z; xl[o4*4+3][node]=v.w;
    }
    __syncthreads();

    const int j = tid;
    float acc1[8] = {0,0,0,0,0,0,0,0};
    float acc2[8] = {0,0,0,0,0,0,0,0};
    const int o2 = j + 128;               // p1-index in [128,384)
    const int v2 = o2/3, m2 = o2%3;

    if (j < 128){
        for (int u = 0; u < 128; ++u){
            float w1 = Wp0[u*128 + j];
            float w2 = Wp1[u*128 + v2];
            fma8(acc1, &xl[u][0], w1);
            fma8(acc2, &xl[128 + u*3 + m2][0], w2);
        }
        float b = bp0[j];
        #pragma unroll
        for (int n = 0; n < 8; ++n) p0l[n][j] = acc1[n] + b;
    } else {
        const int o1 = j - 128, v1 = o1/3, m1 = o1%3;
        for (int u = 0; u < 128; ++u){
            float w1 = Wp1[u*128 + v1];
            float w2 = Wp1[u*128 + v2];
            fma8(acc1, &xl[128 + u*3 + m1][0], w1);
            fma8(acc2, &xl[128 + u*3 + m2][0], w2);
        }
        #pragma unroll
        for (int n = 0; n < 8; ++n) p1[(size_t)(n0+n)*384 + (j-128)] = acc1[n];
    }
    #pragma unroll
    for (int n = 0; n < 8; ++n) p1[(size_t)(n0+n)*384 + o2] = acc2[n];
    __syncthreads();

    // sdst = p0 @ (Ws1[0:128] + Ws1[128:256])  (the dst-only part of s0@W_s1)
    {
        int n = tid >> 5, h = tid & 31;
        float s = 0.f;
        for (int u = 0; u < 128; ++u){
            float wc = Ws1[u*32 + h] + Ws1[(128+u)*32 + h];
            s += p0l[n][u] * wc;
        }
        sdst[(size_t)(n0+n)*32 + h] = s;
    }
}

// ---------------- K2: gate + node irrep_linear -> self_x -------------------
__global__ __launch_bounds__(256) void k_gate_nd(
    const float* __restrict__ x,
    const float* __restrict__ Wg1, const float* __restrict__ bg1,
    const float* __restrict__ Wg2, const float* __restrict__ bg2,
    const float* __restrict__ Wnd0, const float* __restrict__ bnd0,
    const float* __restrict__ Wnd1,
    float* __restrict__ self_x)
{
    __shared__ float xl[512][8];
    __shared__ float tl[256][8];   // t, then reused for g
    __shared__ float hl[256][8];
    const int tid = threadIdx.x;
    const int n0 = blockIdx.x * 8;

    for (int it = 0; it < 4; ++it){
        int idx = tid + 256*it;
        int node = idx >> 7, o4 = idx & 127;
        float4 v = ((const float4*)(x + (size_t)(n0+node)*512))[o4];
        xl[o4*4+0][node]=v.x; xl[o4*4+1][node]=v.y;
        xl[o4*4+2][node]=v.z; xl[o4*4+3][node]=v.w;
    }
    __syncthreads();

    { // t = [x0, n1]
        int jj = tid;
        if (jj < 128){
            #pragma unroll
            for (int n = 0; n < 8; ++n) tl[jj][n] = xl[jj][n];
        } else {
            int u = jj - 128;
            #pragma unroll
            for (int n = 0; n < 8; ++n){
                float a = xl[128+u*3][n], b = xl[128+u*3+1][n], c = xl[128+u*3+2][n];
                tl[jj][n] = sqrtf((a*a + b*b + c*c) * (1.f/3.f));
            }
        }
    }
    __syncthreads();

    { // h = silu(t @ Wg1 + bg1)
        float acc[8] = {0,0,0,0,0,0,0,0};
        for (int k = 0; k < 256; ++k){
            float w = Wg1[k*256 + tid];
            fma8(acc, &tl[k][0], w);
        }
        float b = bg1[tid];
        #pragma unroll
        for (int n = 0; n < 8; ++n){
            float v = acc[n] + b;
            hl[tid][n] = v / (1.f + expf(-v));
        }
    }
    __syncthreads();

    { // g = h @ Wg2 + bg2  (stored into tl; tl is dead after the barrier)
        float acc[8] = {0,0,0,0,0,0,0,0};
        for (int k = 0; k < 256; ++k){
            float w = Wg2[k*256 + tid];
            fma8(acc, &hl[k][0], w);
        }
        float b = bg2[tid];
        #pragma unroll
        for (int n = 0; n < 8; ++n) tl[tid][n] = acc[n] + b;
    }
    __syncthreads();

    { // xg in-place into xl
        int jj = tid;
        if (jj < 128){
            #pragma unroll
            for (int n = 0; n < 8; ++n) xl[jj][n] = tl[jj][n];
        } else {
            int u = jj - 128;
            #pragma unroll
            for (int n = 0; n < 8; ++n){
                float g1 = tl[128+u][n];
                xl[128+u*3  ][n] *= g1;
                xl[128+u*3+1][n] *= g1;
                xl[128+u*3+2][n] *= g1;
            }
        }
    }
    __syncthreads();

    // nd irrep_linear
    const int j = tid;
    float acc1[8] = {0,0,0,0,0,0,0,0};
    float acc2[8] = {0,0,0,0,0,0,0,0};
    const int o2 = j + 128;
    const int v2 = o2/3, m2 = o2%3;
    if (j < 128){
        for (int u = 0; u < 128; ++u){
            float w1 = Wnd0[u*128 + j];
            float w2 = Wnd1[u*128 + v2];
            fma8(acc1, &xl[u][0], w1);
            fma8(acc2, &xl[128 + u*3 + m2][0], w2);
        }
        float b = bnd0[j];
        #pragma unroll
        for (int n = 0; n < 8; ++n) self_x[(size_t)(n0+n)*512 + j] = acc1[n] + b;
    } else {
        const int o1 = j - 128, v1 = o1/3, m1 = o1%3;
        for (int u = 0; u < 128; ++u){
            float w1 = Wnd1[u*128 + v1];
            float w2 = Wnd1[u*128 + v2];
            fma8(acc1, &xl[128 + u*3 + m1][0], w1);
            fma8(acc2, &xl[128 + u*3 + m2][0], w2);
        }
        #pragma unroll
        for (int n = 0; n < 8; ++n) self_x[(size_t)(n0+n)*512 + j] = acc1[n];
    }
    #pragma unroll
    for (int n = 0; n < 8; ++n) self_x[(size_t)(n0+n)*512 + j + 256] = acc2[n];
}

// ---------------- CSR build: count, scan, fill (arrays hosted in d_out) ----
__global__ __launch_bounds__(256) void k_count(
    const int* __restrict__ eidx, int* __restrict__ cnt)
{
    int e = blockIdx.x * 256 + threadIdx.x;
    if (e < EE){
        int d = eidx[e];
        if (d >= 0 && d < NN) atomicAdd(&cnt[d], 1);
    }
}

__global__ __launch_bounds__(256) void k_scan(
    const int* __restrict__ cnt, int* __restrict__ rowptr, int* __restrict__ cur)
{
    __shared__ int part[256];
    const int t = threadIdx.x;
    const int CHUNK = 79;             // 256*79 = 20224 >= 20000
    const int base = t * CHUNK;
    int s = 0;
    for (int i = 0; i < CHUNK; ++i){
        int idx = base + i;
        if (idx < NN) s += cnt[idx];
    }
    part[t] = s;
    __syncthreads();
    for (int off = 1; off < 256; off <<= 1){
        int v = (t >= off) ? part[t-off] : 0;
        __syncthreads();
        part[t] += v;
        __syncthreads();
    }
    int run = (t == 0) ? 0 : part[t-1];
    for (int i = 0; i < CHUNK; ++i){
        int idx = base + i;
        if (idx < NN){
            rowptr[idx] = run;
            cur[idx]    = run;
            run += cnt[idx];
        }
    }
    if (t == 255) rowptr[NN] = run;
}

__global__ __launch_bounds__(256) void k_fill(
    const int* __restrict__ eidx, int* __restrict__ cur, int2* __restrict__ ebuf,
    int* __restrict__ dstbuf)
{
    int e = blockIdx.x * 256 + threadIdx.x;
    if (e < EE){
        int dst = eidx[e];
        int src = eidx[EE + e];
        if (dst >= 0 && dst < NN){
            int pos = atomicAdd(&cur[dst], 1);
            if (pos >= 0 && pos < EE){
                ebuf[pos] = make_int2(e, src);
                dstbuf[pos] = dst;
            }
        }
    }
}

// ---------------- K3: edge features in CSR order -> fbuf, sbuf -------------
// CSR-consecutive edges share dst => p1[dst]/sdst[dst] gathers are L1/L2
// broadcasts; fbuf/sbuf written by CSR position (contiguous for consumer).
__global__ __launch_bounds__(256) void k_edge_pre(
    const float* __restrict__ p1g, const float* __restrict__ sdst,
    const float* __restrict__ ea,
    const int2* __restrict__ ebuf, const int* __restrict__ dstbuf,
    const float* __restrict__ Wf1, const float* __restrict__ Ws1,
    float* __restrict__ fbuf, float* __restrict__ sbuf)
{
    __shared__ float p1d[8][384], p1s[8][384];
    __shared__ float eal[8][32], sdl[8][32];
    __shared__ float ip1l[8][128];
    __shared__ int eidl[8], srcl[8], dstl[8];
    const int tid = threadIdx.x;
    const long e0 = (long)blockIdx.x * 8;

    if (tid < 8){
        int2 pe = ebuf[e0 + tid];
        if (!(pe.x >= 0 && pe.x < EE)) pe.x = 0;
        if (!(pe.y >= 0 && pe.y < NN)) pe.y = 0;
        int d = dstbuf[e0 + tid];
        if (!(d >= 0 && d < NN)) d = 0;
        eidl[tid] = pe.x; srcl[tid] = pe.y; dstl[tid] = d;
    }
    __syncthreads();

    for (int e = 0; e < 8; ++e){
        int dst = dstl[e], src = srcl[e], eid = eidl[e];
        if (tid < 96)
            ((float4*)p1d[e])[tid] = ((const float4*)(p1g + (size_t)dst*384))[tid];
        else if (tid < 192)
            ((float4*)p1s[e])[tid-96] = ((const float4*)(p1g + (size_t)src*384))[tid-96];
        else if (tid < 200)
            ((float4*)eal[e])[tid-192] = ((const float4*)(ea + (size_t)eid*32))[tid-192];
        else if (tid < 208)
            ((float4*)sdl[e])[tid-200] = ((const float4*)(sdst + (size_t)dst*32))[tid-200];
    }
    __syncthreads();

    for (int it = 0; it < 4; ++it){
        int idx = tid + 256*it;
        int e = idx >> 7, u = idx & 127;
        ip1l[e][u] = (p1d[e][u*3]*p1s[e][u*3] + p1d[e][u*3+1]*p1s[e][u*3+1]
                    + p1d[e][u*3+2]*p1s[e][u*3+2]) * (1.f/3.f);
    }
    __syncthreads();

    {
        int e = tid >> 5, h = tid & 31;
        float f = 0.f;
        for (int k = 0; k < 32; ++k) f += eal[e][k] * Wf1[k*32 + h];
        float s = sdl[e][h];
        for (int u = 0; u < 128; ++u) s += ip1l[e][u] * Ws1[(256+u)*32 + h];
        fbuf[(e0+e)*32 + h] = sspf(f);
        sbuf[(e0+e)*32 + h] = sspf(s);
    }
}

// ---------------- fused edge GEMM + epilogue + segment reduction -----------
// Block = 64 CSR-ordered edges, 256 threads. Thread pair = channel c (0..127),
// half h. Each thread keeps 4 weight columns (128 VGPRs) for its 2 quadrants:
// h=0 -> (w1,w2), h=1 -> (w3,w4). Per edge: uniform LDS-broadcast fb/sb reads,
// 128 all-register FMA, one shfl_xor(1) to swap quadrant pairs. Outputs are
// accumulated in registers across each dst-segment (CSR-contiguous); interior
// segments direct-store, boundary segments atomicAdd to pre-zeroed out.
__global__ __launch_bounds__(256) void k_edge_one(
    const float* __restrict__ fbuf, const float* __restrict__ sbuf,
    const float* __restrict__ self_x, const float* __restrict__ esh,
    const int2* __restrict__ ebuf, const int* __restrict__ dstbuf,
    const float* __restrict__ Wf2, const float* __restrict__ Ws2,
    float* __restrict__ out)
{
    __shared__ float fbl[64][32];
    __shared__ float sbl[64][32];
    __shared__ float shl[64][4];
    __shared__ int   srcl[64], dl[64];

    const int tid = threadIdx.x;
    const int c   = tid >> 1;          // channel 0..127
    const int h   = tid & 1;           // half: 0 -> (w1,w2), 1 -> (w3,w4)
    const long e0 = (long)blockIdx.x * 64;
    const float IS3 = 0.57735026919f;

    // weight columns for quadrants qA=2h, qB=2h+1 (held in registers)
    float wfA[32], wfB[32], wsA[32], wsB[32];
    {
        const int qA = 2*h*128 + c, qB = (2*h+1)*128 + c;
        #pragma unroll
        for (int k = 0; k < 32; ++k){
            wfA[k] = Wf2[(size_t)k*512 + qA];
            wfB[k] = Wf2[(size_t)k*512 + qB];
            wsA[k] = Ws2[(size_t)k*512 + qA];
            wsB[k] = Ws2[(size_t)k*512 + qB];
        }
    }

    if (tid < 64){
        int2 pe = ebuf[e0 + tid];
        if (!(pe.x >= 0 && pe.x < EE)) pe.x = 0;
        if (!(pe.y >= 0 && pe.y < NN)) pe.y = 0;
        int d = dstbuf[e0 + tid];
        if (!(d >= 0 && d < NN)) d = 0;
        srcl[tid] = pe.y; dl[tid] = d;
        ((float4*)shl)[tid] = ((const float4*)esh)[pe.x];
    }
    { // fbuf/sbuf CSR-contiguous: fully coalesced copy, 512 float4 each
        const float4* fsrc = (const float4*)(fbuf + (size_t)e0*32);
        const float4* ssrc = (const float4*)(sbuf + (size_t)e0*32);
        ((float4*)fbl)[tid]       = fsrc[tid];
        ((float4*)fbl)[tid + 256] = fsrc[tid + 256];
        ((float4*)sbl)[tid]       = ssrc[tid];
        ((float4*)sbl)[tid + 256] = ssrc[tid + 256];
    }
    __syncthreads();

    // neighbor dsts for boundary detection (block-uniform)
    const int dprev = (blockIdx.x == 0)    ? -1 : dstbuf[e0 - 1];
    const int dnext = (e0 + 64 < EE)       ? dstbuf[e0 + 64] : -1;

    float a0 = 0.f, a1 = 0.f;
    int sstart = 0;

    // prefetch sx values for edge 0
    const float* sx0 = self_x + (size_t)srcl[0]*512;
    float px = sx0[c];
    float p0 = sx0[128 + 3*c];
    float p1v = sx0[128 + 3*c + 1];
    float p2 = sx0[128 + 3*c + 2];

    for (int e = 0; e < 64; ++e){
        const float x0c = px, v0 = p0, v1 = p1v, v2 = p2;
        if (e < 63){
            const float* sx = self_x + (size_t)srcl[e+1]*512;
            px  = sx[c];
            p0  = sx[128 + 3*c];
            p1v = sx[128 + 3*c + 1];
            p2  = sx[128 + 3*c + 2];
        }

        // dual quadrant dots (all-register FMA; fb/sb are LDS broadcasts)
        float FA = 0.f, FB = 0.f, SA = 0.f, SB = 0.f;
        #pragma unroll
        for (int k4 = 0; k4 < 8; ++k4){
            float4 fb4 = *(const float4*)&fbl[e][k4*4];
            float4 sb4 = *(const float4*)&sbl[e][k4*4];
            FA += fb4.x*wfA[k4*4+0]; FB += fb4.x*wfB[k4*4+0];
            SA += sb4.x*wsA[k4*4+0]; SB += sb4.x*wsB[k4*4+0];
            FA += fb4.y*wfA[k4*4+1]; FB += fb4.y*wfB[k4*4+1];
            SA += sb4.y*wsA[k4*4+1]; SB += sb4.y*wsB[k4*4+1];
            FA += fb4.z*wfA[k4*4+2]; FB += fb4.z*wfB[k4*4+2];
            SA += sb4.z*wsA[k4*4+2]; SB += sb4.z*wsB[k4*4+2];
            FA += fb4.w*wfA[k4*4+3]; FB += fb4.w*wfB[k4*4+3];
            SA += sb4.w*wsA[k4*4+3]; SB += sb4.w*wsB[k4*4+3];
        }
        const float wA = FA*SA, wB = FB*SB;
        const float oA = __shfl_xor(wA, 1);
        const float oB = __shfl_xor(wB, 1);
        // h=0: w1=wA w2=wB w3=oA w4=oB ; h=1: w1=oA w2=oB w3=wA w4=wB
        const float w1 = h ? oA : wA;
        const float w2 = h ? oB : wB;
        const float w3 = h ? wA : oA;
        const float w4 = h ? wB : oB;

        const float4 sh = *(const float4*)&shl[e][0];
        const int dste = dl[e];

        const float dot = v0*sh.y + v1*sh.z + v2*sh.w;
        // h=0: a0 = out0[c],    a1 = out1[c][0]
        // h=1: a0 = out1[c][1], a1 = out1[c][2]
        const float caw = h ? w2 : w1;
        const float cf  = h ? sh.z : sh.x;
        const float cbw = h ? w3 : w4*IS3;
        const float cg  = h ? v1*sh.x : dot;
        a0 += caw*x0c*cf + cbw*cg;
        const float shm = h ? sh.w : sh.y;
        const float vm  = h ? v2 : v0;
        a1 += w2*x0c*shm + w3*vm*sh.x;

        if (e == 63 || dl[e+1] != dste){   // block-uniform segment end
            const bool openL = (sstart == 0) && (dprev == dste);
            const bool openR = (e == 63) && (dnext == dste);
            float* orow = out + (size_t)dste*512;
            const int pos0 = h ? (128 + 3*c + 1) : c;
            const int pos1 = h ? (128 + 3*c + 2) : (128 + 3*c);
            if (openL || openR){
                atomicAdd(orow + pos0, a0);
                atomicAdd(orow + pos1, a1);
            } else {
                orow[pos0] = a0;
                orow[pos1] = a1;
            }
            a0 = 0.f; a1 = 0.f; sstart = e + 1;
        }
    }
}

// ---------------- K5: out linear + residual (in-place over d_out) ----------
__global__ __launch_bounds__(256) void k_post(
    const float* __restrict__ self_x, const float* __restrict__ x,
    const float* __restrict__ Wo0, const float* __restrict__ bo0,
    const float* __restrict__ Wo1,
    float* __restrict__ out)
{
    __shared__ float tl[512][8];
    const int tid = threadIdx.x;
    const int n0 = blockIdx.x * 8;

    for (int it = 0; it < 4; ++it){
        int idx = tid + 256*it;
        int node = idx >> 7, o4 = idx & 127;
        float4 a = ((const float4*)(out    + (size_t)(n0+node)*512))[o4];
        float4 b = ((const float4*)(self_x + (size_t)(n0+node)*512))[o4];
        tl[o4*4+0][node]=a.x+b.x; tl[o4*4+1][node]=a.y+b.y;
        tl[o4*4+2][node]=a.z+b.z; tl[o4*4+3][node]=a.w+b.w;
    }
    __syncthreads();

    const int j = tid;
    float acc1[8] = {0,0,0,0,0,0,0,0};
    float acc2[8] = {0,0,0,0,0,0,0,0};
    const int o2 = j + 128;
    const int v2 = o2/3, m2 = o2%3;
    if (j < 128){
        for (int u = 0; u < 128; ++u){
            float w1 = Wo0[u*128 + j];
            float w2 = Wo1[u*128 + v2];
            fma8(acc1, &tl[u][0], w1);
            fma8(acc2, &tl[128 + u*3 + m2][0], w2);
        }
        float b = bo0[j];
        #pragma unroll
        for (int n = 0; n < 8; ++n)
            out[(size_t)(n0+n)*512 + j] = acc1[n] + b + x[(size_t)(n0+n)*512 + j];
    } else {
        const int o1 = j - 128, v1 = o1/3, m1 = o1%3;
        for (int u = 0; u < 128; ++u){
            float w1 = Wo1[u*128 + v1];
            float w2 = Wo1[u*128 + v2];
            fma8(acc1, &tl[128 + u*3 + m1][0], w1);
            fma8(acc2, &tl[128 + u*3 + m2][0], w2);
        }
        #pragma unroll
        for (int n = 0; n < 8; ++n)
            out[(size_t)(n0+n)*512 + j] = acc1[n] + x[(size_t)(n0+n)*512 + j];
    }
    #pragma unroll
    for (int n = 0; n < 8; ++n)
        out[(size_t)(n0+n)*512 + j + 256] = acc2[n] + x[(size_t)(n0+n)*512 + j + 256];
}

// ---------------------------------------------------------------------------
extern "C" void kernel_launch(void* const* d_in, const int* in_sizes, int n_in,
                              void* d_out, int out_size, void* d_ws, size_t ws_size,
                              hipStream_t stream)
{
    const float* x    = (const float*)d_in[0];
    const float* esh  = (const float*)d_in[1];
    const float* ea   = (const float*)d_in[2];
    const int*   eidx = (const int*)  d_in[3];
    const float* Wp0  = (const float*)d_in[4];
    const float* bp0  = (const float*)d_in[5];
    const float* Wp1  = (const float*)d_in[6];
    const float* Wnd0 = (const float*)d_in[7];
    const float* bnd0 = (const float*)d_in[8];
    const float* Wnd1 = (const float*)d_in[9];
    const float* Wg1  = (const float*)d_in[10];
    const float* bg1  = (const float*)d_in[11];
    const float* Wg2  = (const float*)d_in[12];
    const float* bg2  = (const float*)d_in[13];
    const float* Wf1  = (const float*)d_in[14];
    const float* Wf2  = (const float*)d_in[15];
    const float* Ws1  = (const float*)d_in[16];
    const float* Ws2  = (const float*)d_in[17];
    const float* Wo0  = (const float*)d_in[18];
    const float* bo0  = (const float*)d_in[19];
    const float* Wo1  = (const float*)d_in[20];

    float* out  = (float*)d_out;
    float* ws   = (float*)d_ws;
    float* p1   = ws;                              // N*384 (dead after k_edge_pre)
    float* sdst = p1   + (size_t)NN*384;           // N*32
    float* sfx  = sdst + (size_t)NN*32;            // N*512
    float* fbuf = sfx  + (size_t)NN*512;           // E*32 (CSR-position order)
    float* sbuf = fbuf + (size_t)EE*32;            // E*32

    // CSR build arrays hosted in d_out (2.64 MB of 41 MB; out not needed yet)
    int*  dcnt  = (int*)d_out;                  // NN
    int*  dcur  = dcnt + NN;                    // NN
    int*  drow  = dcur + NN;                    // NN+1 (+3 pad for alignment)
    int2* debuf = (int2*)(drow + NN + 4);       // E int2 (byte 240016, 8-aligned)
    int*  ddst  = (int*)(debuf + EE);           // E int (contiguous after debuf)

    // CSR build first (needs only eidx)
    hipMemsetAsync(dcnt, 0, (size_t)NN*sizeof(int), stream);
    k_count <<<(EE+255)/256, 256, 0, stream>>>(eidx, dcnt);
    k_scan  <<<1, 256, 0, stream>>>(dcnt, drow, dcur);
    k_fill  <<<(EE+255)/256, 256, 0, stream>>>(eidx, dcur, debuf, ddst);

    k_pre     <<<NN/8, 256, 0, stream>>>(x, Wp0, bp0, Wp1, Ws1, p1, sdst);
    k_gate_nd <<<NN/8, 256, 0, stream>>>(x, Wg1, bg1, Wg2, bg2, Wnd0, bnd0, Wnd1, sfx);
    k_edge_pre<<<EE/8, 256, 0, stream>>>(p1, sdst, ea, debuf, ddst, Wf1, Ws1,
                                         fbuf, sbuf);

    // p1 now dead: move CSR (ebuf+dstbuf, contiguous 2.4 MB) into its region,
    // then zero out for the scatter.
    int2* ebuf2   = (int2*)ws;
    int*  dstbuf2 = (int*)ws + (size_t)2*EE;
    hipMemcpyAsync(ws, debuf, (size_t)3*EE*sizeof(int),
                   hipMemcpyDeviceToDevice, stream);
    hipMemsetAsync(out, 0, (size_t)NN*512*sizeof(float), stream);

    k_edge_one<<<EE/64, 256, 0, stream>>>(fbuf, sbuf, sfx, esh, ebuf2, dstbuf2,
                                          Wf2, Ws2, out);

    k_post    <<<NN/8, 256, 0, stream>>>(sfx, x, Wo0, bo0, Wo1, out);
}